// Round 9
// baseline (4565.314 us; speedup 1.0000x reference)
//
#include <hip/hip_runtime.h>
#include <hip/hip_bf16.h>
#include <math.h>

// Problem dims
#define DI 69      // input feature dim
#define EE 132     // time2vec dim
#define RR 1024    // rnn size
#define BB 2048    // batch
#define TT 25      // target seq len
#define SE 49      // source seq len - 1

typedef _Float16 f16;
typedef _Float16 v8h __attribute__((ext_vector_type(8)));
typedef float f32x4 __attribute__((ext_vector_type(4)));

__device__ __forceinline__ float sigm(float x) { return 1.0f / (1.0f + __expf(-x)); }
__device__ __forceinline__ float tanhf_fast(float x) {
  float e = __expf(2.0f * x);          // inf-safe: x>>0 -> 1, x<<0 -> -1
  return 1.0f - 2.0f / (e + 1.0f);
}

// All GEMMs consume operands DIRECTLY from global as per-lane MFMA fragments
// (no LDS, no barriers, no swizzle). mfma_f32_16x16x32_f16 fragment maps:
//   A: lane l holds A[row16 + (l&15)][k32 + (l>>4)*8 .. +8]   (v8h, 16B)
//   B: lane l holds B[col16 + (l&15)][k32 + (l>>4)*8 .. +8]
//   C: col = lane&15, row = (lane>>4)*4 + q
// Weights are pre-packed in fragment order: block(u16-tile, kt, gate) of
// 512 halves, half index = ((k>>3)&3)<<4 | (u&15))*8 + (k&7), so a wave
// loads one fragment with a single coalesced dwordx4 at base + lane*16.

// ---------------- prep kernels ----------------

__global__ void prep_misc_kernel(float* __restrict__ c, f16* __restrict__ h0,
                                 const float* __restrict__ bih_e, const float* __restrict__ bhh_e,
                                 const float* __restrict__ bih_d, const float* __restrict__ bhh_d,
                                 float* __restrict__ bias_e, float* __restrict__ bias_d,
                                 const float* __restrict__ fc1_w, f16* __restrict__ fc1f,
                                 const float* __restrict__ t2v_w, f16* __restrict__ wt2f)
{
  int i = blockIdx.x * 256 + threadIdx.x;   // grid covers BB*RR = 2M
  if (i < BB * RR) { c[i] = 0.0f; h0[i] = (f16)0.0f; }
  if (i < 4096) { bias_e[i] = bih_e[i] + bhh_e[i]; bias_d[i] = bih_d[i] + bhh_d[i]; }
  if (i < 80 * RR) {   // fc1 fragment pack: [kt 0..31][nt 0..4][512]
    int u = i >> 10, k = i & 1023;
    size_t dst = ((size_t)(k >> 5) * 5 + (u >> 4)) * 512
               + ((((k >> 3) & 3) << 4) | (u & 15)) * 8 + (k & 7);
    fc1f[dst] = (f16)((u < DI) ? fc1_w[u * RR + k] : 0.0f);
  }
  if (i < 160 * 128) { // t2v fragment pack: [kt 0..3][nt 0..9][512]
    int e = i >> 7, k = i & 127;
    size_t dst = ((size_t)(k >> 5) * 10 + (e >> 4)) * 512
               + ((((k >> 3) & 3) << 4) | (e & 15)) * 8 + (k & 7);
    wt2f[dst] = (f16)((e < EE && k < DI) ? t2v_w[e * DI + k] : 0.0f);
  }
}

// Fragment-pack gate weights. Wqf block layout: [(u>>4)*NKT + kt][g][512].
// k<1024 = Whh row, k>=1024 = Wih row (feature part), zero-padded.
__global__ void prep_wqf_kernel(const float* __restrict__ Whh, const float* __restrict__ Wih,
                                f16* __restrict__ Wqf, int NKT, int DIN)
{
  int idx = blockIdx.x * 256 + threadIdx.x;   // one 8-half fragment piece each
  int tot = 4096 * NKT * 4;
  if (idx >= tot) return;
  int j = idx / (NKT * 4);                    // W row = g*1024 + u
  int k8 = (idx - j * (NKT * 4)) * 8;         // k base (multiple of 8)
  int g = j >> 10, u = j & 1023;
  f16 v[8];
  if (k8 < 1024) {
    const float* s = Whh + (size_t)j * RR + k8;
    #pragma unroll
    for (int e = 0; e < 8; ++e) v[e] = (f16)s[e];
  } else {
    int kk = k8 - 1024;
    #pragma unroll
    for (int e = 0; e < 8; ++e) v[e] = (f16)((kk + e < DIN) ? Wih[(size_t)j * DIN + kk + e] : 0.0f);
  }
  size_t dst = (((size_t)(u >> 4) * NKT + (k8 >> 5)) * 4 + g) * 512
             + ((((k8 >> 3) & 3) << 4) | (u & 15)) * 8;
  *(v8h*)(Wqf + dst) = *(v8h*)v;
}

// Xf[row][128] = f16 x (pad 0); feat_e[row][256]: cols 0..68 = x, 201..255 = 0.
// (t2v_kernel fills cols 69..200.)
__global__ void xf16_kernel(const float* __restrict__ enc_in,
                            f16* __restrict__ Xf, f16* __restrict__ feat)
{
  int idx = blockIdx.x * 256 + threadIdx.x;   // over SE*BB*256
  if (idx >= SE * BB * 256) return;
  int j = idx & 255, row = idx >> 8;          // row = t*BB + b
  int t = row >> 11, b = row & (BB - 1);
  if (j < 128) {
    float v = (j < DI) ? enc_in[(size_t)b * SE * DI + t * DI + j] : 0.0f;
    Xf[(size_t)row * 128 + j] = (f16)v;
    if (j < DI) feat[(size_t)row * 256 + j] = (f16)v;
  } else if (j >= 201) {
    feat[(size_t)row * 256 + j] = (f16)0.0f;
  }
}

// sin(X @ Wt2^T + b) -> feat cols 69..200. No LDS: per-lane fragment loads.
__global__ __launch_bounds__(256)
void t2v_kernel(const f16* __restrict__ Xf, const f16* __restrict__ wt2f,
                const float* __restrict__ t2v_b, f16* __restrict__ feat)
{
  const int tid = threadIdx.x;
  const int m0 = blockIdx.x * 128;             // row = t*BB + b
  const int lane = tid & 63, w = tid >> 6;
  const int lrow = lane & 15, slot = lane >> 4;

  const f16* pA[2];
  #pragma unroll
  for (int mf = 0; mf < 2; ++mf)
    pA[mf] = Xf + (size_t)(m0 + w * 32 + mf * 16 + lrow) * 128 + slot * 8;
  const f16* pB = wt2f + lane * 8;

  f32x4 acc[2][10];
  #pragma unroll
  for (int a = 0; a < 2; ++a)
    #pragma unroll
    for (int n = 0; n < 10; ++n) acc[a][n] = (f32x4){0.f, 0.f, 0.f, 0.f};

  #pragma unroll
  for (int kt = 0; kt < 4; ++kt) {
    v8h a[2], b[10];
    #pragma unroll
    for (int mf = 0; mf < 2; ++mf) a[mf] = *(const v8h*)(pA[mf] + kt * 32);
    #pragma unroll
    for (int nf = 0; nf < 10; ++nf) b[nf] = *(const v8h*)(pB + (size_t)(kt * 10 + nf) * 512);
    #pragma unroll
    for (int mf = 0; mf < 2; ++mf)
      #pragma unroll
      for (int nf = 0; nf < 10; ++nf)
        acc[mf][nf] = __builtin_amdgcn_mfma_f32_16x16x32_f16(a[mf], b[nf], acc[mf][nf], 0, 0, 0);
  }
  #pragma unroll
  for (int nf = 0; nf < 10; ++nf) {
    int e = nf * 16 + lrow;
    if (e < EE) {
      float be = t2v_b[e];
      #pragma unroll
      for (int mf = 0; mf < 2; ++mf) {
        int rbase = m0 + w * 32 + mf * 16 + slot * 4;
        #pragma unroll
        for (int q = 0; q < 4; ++q) {
          int row = rbase + q;
          feat[(size_t)row * 256 + 69 + e] = (f16)__sinf(acc[mf][nf][q] + be);
        }
      }
    }
  }
}

// feat_dec[t*BB+b][0:69] = decoder_inputs[b][t][:], [69:128]=0  (f16, plain)
__global__ void feat_dec_kernel(const float* __restrict__ dec_in, f16* __restrict__ feat)
{
  int idx = blockIdx.x * 256 + threadIdx.x;
  if (idx >= TT * BB * 128) return;
  int k = idx & 127;
  int r = idx >> 7;              // t*BB + b
  int t = r >> 11, b = r & (BB - 1);
  feat[idx] = (f16)((k < DI) ? dec_in[(size_t)b * TT * DI + t * DI + k] : 0.0f);
}

// ---------------- fused LSTM step: gates GEMM + cell update ----------------
// Block: 128 rows x 32 units (x4 gates). 4 waves (wm,wn). NO LDS, NO barriers:
// A per-lane fragment loads from h/feat (plain), B coalesced fragment loads
// from Wqf. 2-deep register pipeline; full unroll folds A offsets to imms.
template<int NKT, int FPAD, bool WF32>
__global__ __launch_bounds__(256, 2)
void lstm_step_kernel(const f16* __restrict__ hin, const f16* __restrict__ feat,
                      const f16* __restrict__ Wqf, const float* __restrict__ bias,
                      float* __restrict__ c, f16* __restrict__ hout,
                      float* __restrict__ hf32)
{
  const int tid = threadIdx.x;
  const int m0 = blockIdx.y * 128;
  const int u0 = blockIdx.x * 32;
  const int lane = tid & 63, w = tid >> 6;
  const int wm = w >> 1, wn = w & 1;
  const int lrow = lane & 15, slot = lane >> 4;

  const f16* pAh[4]; const f16* pAf[4];
  #pragma unroll
  for (int mf = 0; mf < 4; ++mf) {
    int row = m0 + wm * 64 + mf * 16 + lrow;
    pAh[mf] = hin + (size_t)row * RR + slot * 8;
    pAf[mf] = feat + (size_t)row * FPAD + slot * 8;
  }
  const int ut = (u0 >> 4) + wn;
  const f16* pB = Wqf + (size_t)ut * NKT * 4 * 512 + lane * 8;

  f32x4 acc[4][4];   // [m-frag][gate]
  #pragma unroll
  for (int a = 0; a < 4; ++a)
    #pragma unroll
    for (int g = 0; g < 4; ++g) acc[a][g] = (f32x4){0.f, 0.f, 0.f, 0.f};

  auto LAh = [&](int kt, v8h (&d)[4]) {
    #pragma unroll
    for (int mf = 0; mf < 4; ++mf) d[mf] = *(const v8h*)(pAh[mf] + kt * 32);
  };
  auto LAf = [&](int j, v8h (&d)[4]) {
    #pragma unroll
    for (int mf = 0; mf < 4; ++mf) d[mf] = *(const v8h*)(pAf[mf] + j * 32);
  };
  auto LB = [&](int kt, v8h (&d)[4]) {
    #pragma unroll
    for (int g = 0; g < 4; ++g) d[g] = *(const v8h*)(pB + (size_t)(kt * 4 + g) * 512);
  };
  auto MM = [&](const v8h (&a)[4], const v8h (&b)[4]) {
    #pragma unroll
    for (int mf = 0; mf < 4; ++mf)
      #pragma unroll
      for (int g = 0; g < 4; ++g)
        acc[mf][g] = __builtin_amdgcn_mfma_f32_16x16x32_f16(a[mf], b[g], acc[mf][g], 0, 0, 0);
  };

  v8h A0[4], B0[4], A1[4], B1[4];
  LAh(0, A0); LB(0, B0);
  #pragma unroll
  for (int kt = 0; kt < 32; kt += 2) {      // h region: kt 0..31
    LAh(kt + 1, A1); LB(kt + 1, B1);
    MM(A0, B0);
    if (kt + 2 < 32) LAh(kt + 2, A0); else LAf(0, A0);
    LB(kt + 2, B0);
    MM(A1, B1);
  }
  #pragma unroll
  for (int kt = 32; kt < NKT; kt += 2) {    // feat region (NKT even)
    LAf(kt + 1 - 32, A1); LB(kt + 1, B1);
    MM(A0, B0);
    if (kt + 2 < NKT) { LAf(kt + 2 - 32, A0); LB(kt + 2, B0); }
    MM(A1, B1);
  }

  // epilogue: gate order i,f,g,o ; C layout col=lane&15, row=slot*4+q
  const int u = u0 + wn * 16 + lrow;
  const float bi = bias[u], bf = bias[1024 + u], bg = bias[2048 + u], bo = bias[3072 + u];
  #pragma unroll
  for (int mf = 0; mf < 4; ++mf) {
    int rbase = m0 + wm * 64 + mf * 16 + slot * 4;
    #pragma unroll
    for (int q = 0; q < 4; ++q) {
      int r = rbase + q;
      size_t idxc = (size_t)r * RR + u;
      float iv = acc[mf][0][q] + bi;
      float fv = acc[mf][1][q] + bf;
      float gv = acc[mf][2][q] + bg;
      float ov = acc[mf][3][q] + bo;
      float cn = sigm(fv) * c[idxc] + sigm(iv) * tanhf_fast(gv);
      float hn = sigm(ov) * tanhf_fast(cn);
      c[idxc] = cn;
      hout[idxc] = (f16)hn;
      if (WF32) hf32[idxc] = hn;
    }
  }
}

// ---------------- mu/sigma normalize + noise ----------------
__global__ void musigma_kernel(const float* __restrict__ hf, float* __restrict__ c,
                               const float* __restrict__ noise,
                               const float* __restrict__ mu_w, const float* __restrict__ mu_b,
                               const float* __restrict__ sig_w, const float* __restrict__ sig_b,
                               f16* __restrict__ hout)
{
  int b = blockIdx.x, tid = threadIdx.x;
  __shared__ float red[8];
  __shared__ float musig[2];
  float sh = 0.f, sc = 0.f;
  for (int k = tid; k < RR; k += 256) {
    size_t idx = (size_t)b * RR + k;
    sh += hf[idx] * mu_w[k];
    sc += c[idx] * sig_w[k];
  }
  for (int off = 32; off > 0; off >>= 1) { sh += __shfl_down(sh, off); sc += __shfl_down(sc, off); }
  int wid = tid >> 6;
  if ((tid & 63) == 0) { red[wid] = sh; red[4 + wid] = sc; }
  __syncthreads();
  if (tid == 0) {
    musig[0] = red[0] + red[1] + red[2] + red[3] + mu_b[0];
    musig[1] = red[4] + red[5] + red[6] + red[7] + sig_b[0];
  }
  __syncthreads();
  float mu = musig[0], sg = musig[1];
  for (int k = tid; k < RR; k += 256) {
    size_t idx = (size_t)b * RR + k;
    float n10 = 10.0f * noise[idx];
    float hh = (hf[idx] - mu) / sg + n10;
    float cc = (c[idx] - mu) / sg + n10;
    hout[idx] = (f16)hh;
    c[idx] = cc;
  }
}

// ---------------- final residual projection: out = x + Hdec @ fc1^T + b ----------------
__global__ __launch_bounds__(256)
void final_fc_kernel(const f16* __restrict__ Hd, const f16* __restrict__ fc1f,
                     const float* __restrict__ fb, const float* __restrict__ dec_in,
                     float* __restrict__ out)
{
  const int tid = threadIdx.x;
  const int m0 = blockIdx.x * 128;        // rows = t*BB + b, 51200 total
  const int lane = tid & 63, w = tid >> 6;
  const int lrow = lane & 15, slot = lane >> 4;

  const f16* pA[2];
  #pragma unroll
  for (int mf = 0; mf < 2; ++mf)
    pA[mf] = Hd + (size_t)(m0 + w * 32 + mf * 16 + lrow) * RR + slot * 8;
  const f16* pB = fc1f + lane * 8;

  f32x4 acc[2][5];
  #pragma unroll
  for (int a = 0; a < 2; ++a)
    #pragma unroll
    for (int n = 0; n < 5; ++n) acc[a][n] = (f32x4){0.f, 0.f, 0.f, 0.f};

  #pragma unroll
  for (int kt = 0; kt < 32; ++kt) {
    v8h a[2], b[5];
    #pragma unroll
    for (int mf = 0; mf < 2; ++mf) a[mf] = *(const v8h*)(pA[mf] + kt * 32);
    #pragma unroll
    for (int nf = 0; nf < 5; ++nf) b[nf] = *(const v8h*)(pB + (size_t)(kt * 5 + nf) * 512);
    #pragma unroll
    for (int mf = 0; mf < 2; ++mf)
      #pragma unroll
      for (int nf = 0; nf < 5; ++nf)
        acc[mf][nf] = __builtin_amdgcn_mfma_f32_16x16x32_f16(a[mf], b[nf], acc[mf][nf], 0, 0, 0);
  }
  #pragma unroll
  for (int mf = 0; mf < 2; ++mf) {
    int rbase = m0 + w * 32 + mf * 16 + slot * 4;
    #pragma unroll
    for (int nf = 0; nf < 5; ++nf) {
      int col = nf * 16 + lrow;
      if (col < DI) {
        #pragma unroll
        for (int q = 0; q < 4; ++q) {
          int m = rbase + q;
          int t = m >> 11, b = m & (BB - 1);
          size_t oi = (size_t)b * TT * DI + t * DI + col;
          out[oi] = acc[mf][nf][q] + fb[col] + dec_in[oi];
        }
      }
    }
  }
}

// ---------------- launch ----------------
extern "C" void kernel_launch(void* const* d_in, const int* in_sizes, int n_in,
                              void* d_out, int out_size, void* d_ws, size_t ws_size,
                              hipStream_t stream)
{
  const float* enc_in = (const float*)d_in[0];
  const float* dec_in = (const float*)d_in[1];
  const float* noise  = (const float*)d_in[2];
  const float* Wih_e  = (const float*)d_in[3];
  const float* Whh_e  = (const float*)d_in[4];
  const float* bih_e  = (const float*)d_in[5];
  const float* bhh_e  = (const float*)d_in[6];
  const float* Wih_d  = (const float*)d_in[7];
  const float* Whh_d  = (const float*)d_in[8];
  const float* bih_d  = (const float*)d_in[9];
  const float* bhh_d  = (const float*)d_in[10];
  const float* fc1_w  = (const float*)d_in[11];
  const float* fc1_b  = (const float*)d_in[12];
  const float* mu_w   = (const float*)d_in[13];
  const float* mu_b   = (const float*)d_in[14];
  const float* sig_w  = (const float*)d_in[15];
  const float* sig_b  = (const float*)d_in[16];
  const float* t2v_w  = (const float*)d_in[17];
  const float* t2v_b  = (const float*)d_in[18];
  float* outp = (float*)d_out;

  const int NKT_E = 40;   // 32 h + 8 feat (FPAD 256)
  const int NKT_D = 36;   // 32 h + 4 feat (FPAD 128)

  char* ws = (char*)d_ws;
  size_t off = 0;
  auto alloc = [&](size_t bytes) -> char* {
    char* p = ws + off; off += (bytes + 255) & ~(size_t)255; return p;
  };
  f16*   wq_e   = (f16*)alloc((size_t)64 * NKT_E * 4 * 512 * 2);
  f16*   wq_d   = (f16*)alloc((size_t)64 * NKT_D * 4 * 512 * 2);
  f16*   fc1f   = (f16*)alloc((size_t)32 * 5 * 512 * 2);
  f16*   wt2f   = (f16*)alloc((size_t)4 * 10 * 512 * 2);
  float* bias_e = (float*)alloc(4096 * 4);
  float* bias_d = (float*)alloc(4096 * 4);
  f16*   feat_e = (f16*)alloc((size_t)SE * BB * 256 * 2);
  f16*   feat_d = (f16*)alloc((size_t)TT * BB * 128 * 2);
  f16*   h_ping = (f16*)alloc((size_t)BB * RR * 2);
  f16*   h_pong = (f16*)alloc((size_t)BB * RR * 2);
  float* cbuf   = (float*)alloc((size_t)BB * RR * 4);
  float* hf32   = (float*)alloc((size_t)BB * RR * 4);
  f16*   Hd     = (f16*)alloc((size_t)TT * BB * RR * 2);
  if (off > ws_size) return;   // workspace too small -> clean failure
  f16*   Xf     = Hd;          // alias: Xf lifetime (prep) disjoint from Hd (decoder)

  // prep
  prep_misc_kernel<<<(BB * RR + 255) / 256, 256, 0, stream>>>(
      cbuf, h_ping, bih_e, bhh_e, bih_d, bhh_d, bias_e, bias_d, fc1_w, fc1f, t2v_w, wt2f);
  prep_wqf_kernel<<<(4096 * NKT_E * 4 + 255) / 256, 256, 0, stream>>>(
      Whh_e, Wih_e, wq_e, NKT_E, DI + EE);
  prep_wqf_kernel<<<(4096 * NKT_D * 4 + 255) / 256, 256, 0, stream>>>(
      Whh_d, Wih_d, wq_d, NKT_D, DI);
  xf16_kernel<<<(SE * BB * 256 + 255) / 256, 256, 0, stream>>>(enc_in, Xf, feat_e);
  t2v_kernel<<<SE * (BB / 128), 256, 0, stream>>>(Xf, wt2f, t2v_b, feat_e);
  feat_dec_kernel<<<(TT * BB * 128 + 255) / 256, 256, 0, stream>>>(dec_in, feat_d);

  dim3 sgrid(32, 16, 1);   // 1024/32 units x 2048/128 rows

  // encoder: 49 steps, h ping-pong, c in-place
  f16* hcur = h_ping; f16* hnxt = h_pong;
  for (int t = 0; t < SE; ++t) {
    const f16* ft = feat_e + (size_t)t * BB * 256;
    if (t == SE - 1)
      lstm_step_kernel<NKT_E, 256, true><<<sgrid, 256, 0, stream>>>(
          hcur, ft, wq_e, bias_e, cbuf, hnxt, hf32);
    else
      lstm_step_kernel<NKT_E, 256, false><<<sgrid, 256, 0, stream>>>(
          hcur, ft, wq_e, bias_e, cbuf, hnxt, nullptr);
    f16* tmp = hcur; hcur = hnxt; hnxt = tmp;
  }

  // normalize + noise (reads fp32 h, writes f16 h into h_ping, c in-place)
  musigma_kernel<<<BB, 256, 0, stream>>>(hf32, cbuf, noise, mu_w, mu_b, sig_w, sig_b, h_ping);

  // decoder: 25 steps, h chained through Hd slices
  const f16* din = h_ping;
  for (int t = 0; t < TT; ++t) {
    f16* hout = Hd + (size_t)t * BB * RR;
    lstm_step_kernel<NKT_D, 128, false><<<sgrid, 256, 0, stream>>>(
        din, feat_d + (size_t)t * BB * 128, wq_d, bias_d, cbuf, hout, nullptr);
    din = hout;
  }

  // out = dec_in + Hdec @ fc1^T + fc1_b
  final_fc_kernel<<<(TT * BB) / 128, 256, 0, stream>>>(Hd, fc1f, fc1_b, dec_in, outp);
}

// Round 12
// 2293.662 us; speedup vs baseline: 1.9904x; 1.9904x over previous
//
#include <hip/hip_runtime.h>
#include <hip/hip_bf16.h>
#include <math.h>

// Problem dims
#define DI 69      // input feature dim
#define EE 132     // time2vec dim
#define RR 1024    // rnn size
#define BB 2048    // batch
#define TT 25      // target seq len
#define SE 49      // source seq len - 1

typedef _Float16 f16;
typedef _Float16 v8h __attribute__((ext_vector_type(8)));
typedef float f32x4 __attribute__((ext_vector_type(4)));

__device__ __forceinline__ float sigm(float x) { return 1.0f / (1.0f + __expf(-x)); }
__device__ __forceinline__ float tanhf_fast(float x) {
  float e = __expf(2.0f * x);          // inf-safe: x>>0 -> 1, x<<0 -> -1
  return 1.0f - 2.0f / (e + 1.0f);
}

// async global->LDS, 16B per lane. LDS dest is wave-uniform base; lane l
// writes bytes [base + l*16, base + l*16 + 16) from its own global address.
typedef const __attribute__((address_space(1))) char* gas1p;
typedef __attribute__((address_space(3))) char* las3p;
__device__ __forceinline__ void gld16(const void* g, void* l) {
  __builtin_amdgcn_global_load_lds((gas1p)g, (las3p)l, 16, 0, 0);
}

// Global h/feat/W layouts are PRE-SWIZZLED: element (row, k) lives at
// k' = k ^ ((row&7)<<3) (XOR on 16B-slot bits within each 64-half K-group).
// Staging to LDS is fully linear (global_load_lds); ds_reads apply the
// same XOR -> conflict-free (both-sides rule).

// ---------------- prep kernels ----------------

__global__ void prep_misc_kernel(float* __restrict__ c, f16* __restrict__ h0,
                                 const float* __restrict__ bih_e, const float* __restrict__ bhh_e,
                                 const float* __restrict__ bih_d, const float* __restrict__ bhh_d,
                                 float* __restrict__ bias_e, float* __restrict__ bias_d,
                                 const float* __restrict__ fc1_w, f16* __restrict__ fc1h,
                                 const float* __restrict__ t2v_w, f16* __restrict__ wt2)
{
  int i = blockIdx.x * 256 + threadIdx.x;   // grid covers BB*RR = 2M
  if (i < BB * RR) { c[i] = 0.0f; h0[i] = (f16)0.0f; }
  if (i < 4096) { bias_e[i] = bih_e[i] + bhh_e[i]; bias_d[i] = bih_d[i] + bhh_d[i]; }
  if (i < 128 * RR) {   // fc1h padded to 128 rows, swizzled
    int dr = i >> 10, k = i & 1023;
    int kd = k ^ ((dr & 7) << 3);
    fc1h[(dr << 10) | kd] = (f16)((dr < DI) ? fc1_w[dr * RR + k] : 0.0f);
  }
  if (i < 160 * 128) {  // t2v weights: [160 rows pad][128 k pad], swizzled
    int r = i >> 7, k = i & 127;
    float v = (r < EE && k < DI) ? t2v_w[r * DI + k] : 0.0f;
    wt2[(r << 7) | (k ^ ((r & 7) << 3))] = (f16)v;
  }
}

// Pack per-gate weights: Wq[j][k'], j = gate*1024+unit (torch row order),
// k<1024 = Whh row, k>=1024 = Wih row (feature part), zero-padded to KT.
__global__ void prep_wq_kernel(const float* __restrict__ Whh, const float* __restrict__ Wih,
                               f16* __restrict__ Wq, int KT, int DIN)
{
  int j = blockIdx.x;   // 0..4095
  int xo = (j & 7) << 3;
  for (int k = threadIdx.x; k < KT; k += blockDim.x) {
    float v;
    if (k < RR) v = Whh[(size_t)j * RR + k];
    else { int kk = k - RR; v = (kk < DIN) ? Wih[(size_t)j * DIN + kk] : 0.0f; }
    Wq[(size_t)j * KT + (k ^ xo)] = (f16)v;
  }
}

// Build swizzled f16 X [t][b][128] (pad 69..127 = 0) AND write feat_e's
// x-part (cols 0..68) + zero tail (cols 201..255). Sin part done by t2v_kernel.
__global__ void xf16_kernel(const float* __restrict__ enc_in,
                            f16* __restrict__ Xf, f16* __restrict__ feat)
{
  int idx = blockIdx.x * 256 + threadIdx.x;   // over SE*BB*256
  if (idx >= SE * BB * 256) return;
  int j = idx & 255, row = idx >> 8;          // row = t*BB + b
  int t = row >> 11, b = row & (BB - 1);
  int xo = (b & 7) << 3;
  int k = j ^ xo;                             // deswizzled col
  if (k < 128) {                              // j<128 <=> k<128
    float v = (k < DI) ? enc_in[(size_t)b * SE * DI + t * DI + k] : 0.0f;
    Xf[(size_t)row * 128 + j] = (f16)v;
    if (k < DI) feat[(size_t)row * 256 + j] = (f16)v;
  } else if (k >= 201) {
    feat[(size_t)row * 256 + j] = (f16)0.0f;
  }
}

// sin(X @ Wt2^T + b) -> feat cols 69..200.  MFMA tile: 128 rows x 160 cols,
// K=128 in two 64-k tiles. 256 thr = 4 waves; wave w owns rows w*32..w*32+31.
__global__ __launch_bounds__(256)
void t2v_kernel(const f16* __restrict__ Xf, const f16* __restrict__ wt2,
                const float* __restrict__ t2v_b, f16* __restrict__ feat)
{
  __shared__ __align__(16) f16 lA[128 * 64];   // 16 KB
  __shared__ __align__(16) f16 lB[160 * 64];   // 20 KB
  __shared__ float bl[EE];
  const int tid = threadIdx.x;
  const int m0 = blockIdx.x * 128;             // row = t*BB + b
  const int lane = tid & 63, w = tid >> 6;
  const int lrow = lane & 15;
  const int r8 = lane >> 3, s8 = lane & 7;
  if (tid < EE) bl[tid] = t2v_b[tid];

  f32x4 acc[2][10];
  #pragma unroll
  for (int a = 0; a < 2; ++a)
    #pragma unroll
    for (int n = 0; n < 10; ++n) acc[a][n] = (f32x4){0.f, 0.f, 0.f, 0.f};

  const int sw0 = (((lane >> 4)) ^ s8) * 8;
  const int sw1 = (((lane >> 4) | 4) ^ s8) * 8;

  for (int kt = 0; kt < 2; ++kt) {
    __syncthreads();   // protects bl (kt=0) and lA/lB reuse (kt=1)
    #pragma unroll
    for (int i = 0; i < 4; ++i)
      gld16(Xf + (size_t)(m0 + w * 32 + 8 * i + r8) * 128 + kt * 64 + s8 * 8,
            &lA[(w * 32 + 8 * i) * 64]);
    #pragma unroll
    for (int i = 0; i < 5; ++i)
      gld16(wt2 + (size_t)(w * 40 + 8 * i + r8) * 128 + kt * 64 + s8 * 8,
            &lB[(w * 40 + 8 * i) * 64]);
    __syncthreads();   // drains gld16
    v8h av0[2], av1[2];
    #pragma unroll
    for (int mf = 0; mf < 2; ++mf) {
      av0[mf] = *(const v8h*)(&lA[(w * 32 + mf * 16 + lrow) * 64 + sw0]);
      av1[mf] = *(const v8h*)(&lA[(w * 32 + mf * 16 + lrow) * 64 + sw1]);
    }
    #pragma unroll
    for (int nf = 0; nf < 10; ++nf) {
      v8h bv0 = *(const v8h*)(&lB[(nf * 16 + lrow) * 64 + sw0]);
      v8h bv1 = *(const v8h*)(&lB[(nf * 16 + lrow) * 64 + sw1]);
      #pragma unroll
      for (int mf = 0; mf < 2; ++mf) {
        acc[mf][nf] = __builtin_amdgcn_mfma_f32_16x16x32_f16(av0[mf], bv0, acc[mf][nf], 0, 0, 0);
        acc[mf][nf] = __builtin_amdgcn_mfma_f32_16x16x32_f16(av1[mf], bv1, acc[mf][nf], 0, 0, 0);
      }
    }
  }
  // epilogue: C col=lane&15, row=(lane>>4)*4+q
  #pragma unroll
  for (int nf = 0; nf < 10; ++nf) {
    int e = nf * 16 + lrow;
    if (e < EE) {
      float be = bl[e];
      #pragma unroll
      for (int mf = 0; mf < 2; ++mf) {
        int rbase = m0 + w * 32 + mf * 16 + (lane >> 4) * 4;
        #pragma unroll
        for (int q = 0; q < 4; ++q) {
          int row = rbase + q;
          feat[(size_t)row * 256 + ((69 + e) ^ ((row & 7) << 3))]
              = (f16)__sinf(acc[mf][nf][q] + be);
        }
      }
    }
  }
}

// feat_dec[t][b][0:69] = decoder_inputs[b][t][:], [69:128]=0  (f16, swizzled)
__global__ void feat_dec_kernel(const float* __restrict__ dec_in, f16* __restrict__ feat)
{
  int idx = blockIdx.x * 256 + threadIdx.x;
  if (idx >= TT * BB * 128) return;
  int k = idx & 127;
  int r = idx >> 7;              // t*BB + b
  int t = r >> 11, b = r & (BB - 1);
  float v = (k < DI) ? dec_in[(size_t)b * TT * DI + t * DI + k] : 0.0f;
  feat[((size_t)r << 7) | (k ^ ((b & 7) << 3))] = (f16)v;
}

// ---------------- fused LSTM step: gates GEMM + cell update ----------------
// Block: 128 rows x 32 units (x4 gates out = 128x128). 256 threads = 4 waves.
// Staging: global_load_lds dwordx4, linear LDS; reads XOR-deswizzle.
// Wave w stages A rows w*32..w*32+31 and B gate w; MFMA: wave (wm,wn) owns
// 64 rows x 16 units x 4 gates.  [measured best: ~29us/step, r3 bench]
template<int FT, int FPAD, bool WF32>
__global__ __launch_bounds__(256, 2)
void lstm_step_kernel(const f16* __restrict__ hin, const f16* __restrict__ feat,
                      const f16* __restrict__ Wq, const float* __restrict__ bias,
                      float* __restrict__ c, f16* __restrict__ hout,
                      float* __restrict__ hf32)
{
  constexpr int KT = (16 + FT) * 64;
  __shared__ __align__(16) f16 lA[128 * 64];   // 16 KB, linear
  __shared__ __align__(16) f16 lB[128 * 64];   // 16 KB, linear
  const int tid = threadIdx.x;
  const int m0 = blockIdx.y * 128;
  const int u0 = blockIdx.x * 32;
  const int lane = tid & 63, w = tid >> 6;
  const int wm = w >> 1, wn = w & 1;
  const int lrow = lane & 15;
  const int r8 = lane >> 3, s8 = lane & 7;     // staging: row-in-8, 16B slot

  // staging pointers: 4 gld16 per wave per operand per K-tile
  const f16* pA[4]; const f16* pB[4];
  f16* dA[4]; f16* dB[4];
  #pragma unroll
  for (int i = 0; i < 4; ++i) {
    int rA = w * 32 + 8 * i;
    dA[i] = lA + rA * 64;
    dB[i] = lB + rA * 64;
    pA[i] = hin + (size_t)(m0 + rA + r8) * RR + s8 * 8;
    pB[i] = Wq + (size_t)(w * 1024 + u0 + 8 * i + r8) * KT + s8 * 8;
  }

  f32x4 acc[4][4];   // [m-frag][gate]
  #pragma unroll
  for (int a = 0; a < 4; ++a)
    #pragma unroll
    for (int g = 0; g < 4; ++g) acc[a][g] = (f32x4){0.f, 0.f, 0.f, 0.f};

  // deswizzled read base addrs (halves): slot' = slot ^ (row&7), row&7 == lane&7
  const int sw0 = (((lane >> 4)) ^ s8) * 8;
  const int sw1 = (((lane >> 4) | 4) ^ s8) * 8;
  const f16* a0 = lA + (wm * 64 + lrow) * 64 + sw0;
  const f16* a1 = lA + (wm * 64 + lrow) * 64 + sw1;
  const f16* b0 = lB + (wn * 16 + lrow) * 64 + sw0;
  const f16* b1 = lB + (wn * 16 + lrow) * 64 + sw1;

  for (int kt = 0; kt < 16 + FT; ++kt) {
    if (kt == 16) {   // switch A source from h to feat
      #pragma unroll
      for (int i = 0; i < 4; ++i)
        pA[i] = feat + (size_t)(m0 + w * 32 + 8 * i + r8) * FPAD + s8 * 8;
    }
    #pragma unroll
    for (int i = 0; i < 4; ++i) { gld16(pA[i], dA[i]); pA[i] += 64; }
    #pragma unroll
    for (int i = 0; i < 4; ++i) { gld16(pB[i], dB[i]); pB[i] += 64; }
    __syncthreads();   // drains vmcnt (compiler-inserted)

    v8h av0[4], av1[4], bv0[4], bv1[4];
    #pragma unroll
    for (int mf = 0; mf < 4; ++mf) {
      av0[mf] = *(const v8h*)(a0 + mf * 1024);
      av1[mf] = *(const v8h*)(a1 + mf * 1024);
    }
    #pragma unroll
    for (int g = 0; g < 4; ++g) {
      bv0[g] = *(const v8h*)(b0 + g * 2048);
      bv1[g] = *(const v8h*)(b1 + g * 2048);
    }
    #pragma unroll
    for (int mf = 0; mf < 4; ++mf)
      #pragma unroll
      for (int g = 0; g < 4; ++g) {
        acc[mf][g] = __builtin_amdgcn_mfma_f32_16x16x32_f16(av0[mf], bv0[g], acc[mf][g], 0, 0, 0);
        acc[mf][g] = __builtin_amdgcn_mfma_f32_16x16x32_f16(av1[mf], bv1[g], acc[mf][g], 0, 0, 0);
      }
    __syncthreads();
  }

  // epilogue: gate order i,f,g,o ; C layout col=lane&15, row=(lane>>4)*4+reg
  const int u = u0 + wn * 16 + lrow;
  const float bi = bias[u], bf = bias[1024 + u], bg = bias[2048 + u], bo = bias[3072 + u];
  #pragma unroll
  for (int mf = 0; mf < 4; ++mf) {
    int rbase = m0 + wm * 64 + mf * 16 + (lane >> 4) * 4;
    #pragma unroll
    for (int q = 0; q < 4; ++q) {
      int r = rbase + q;
      size_t idxc = (size_t)r * RR + u;
      float iv = acc[mf][0][q] + bi;
      float fv = acc[mf][1][q] + bf;
      float gv = acc[mf][2][q] + bg;
      float ov = acc[mf][3][q] + bo;
      float cn = sigm(fv) * c[idxc] + sigm(iv) * tanhf_fast(gv);
      float hn = sigm(ov) * tanhf_fast(cn);
      c[idxc] = cn;
      hout[(size_t)r * RR + (u ^ ((r & 7) << 3))] = (f16)hn;   // swizzled
      if (WF32) hf32[idxc] = hn;                                // plain
    }
  }
}

// ---------------- mu/sigma normalize + noise ----------------
__global__ void musigma_kernel(const float* __restrict__ hf, float* __restrict__ c,
                               const float* __restrict__ noise,
                               const float* __restrict__ mu_w, const float* __restrict__ mu_b,
                               const float* __restrict__ sig_w, const float* __restrict__ sig_b,
                               f16* __restrict__ hout)
{
  int b = blockIdx.x, tid = threadIdx.x;
  __shared__ float red[8];
  __shared__ float musig[2];
  float sh = 0.f, sc = 0.f;
  for (int k = tid; k < RR; k += 256) {
    size_t idx = (size_t)b * RR + k;
    sh += hf[idx] * mu_w[k];
    sc += c[idx] * sig_w[k];
  }
  for (int off = 32; off > 0; off >>= 1) { sh += __shfl_down(sh, off); sc += __shfl_down(sc, off); }
  int wid = tid >> 6;
  if ((tid & 63) == 0) { red[wid] = sh; red[4 + wid] = sc; }
  __syncthreads();
  if (tid == 0) {
    musig[0] = red[0] + red[1] + red[2] + red[3] + mu_b[0];
    musig[1] = red[4] + red[5] + red[6] + red[7] + sig_b[0];
  }
  __syncthreads();
  float mu = musig[0], sg = musig[1];
  int xo = (b & 7) << 3;
  for (int k = tid; k < RR; k += 256) {
    size_t idx = (size_t)b * RR + k;
    float n10 = 10.0f * noise[idx];
    float hh = (hf[idx] - mu) / sg + n10;
    float cc = (c[idx] - mu) / sg + n10;
    hout[(size_t)b * RR + (k ^ xo)] = (f16)hh;   // swizzled
    c[idx] = cc;                                  // plain
  }
}

// ---------------- final residual projection: out = x + Hdec @ fc1^T + b ----------------
__global__ __launch_bounds__(256, 2)
void final_fc_kernel(const f16* __restrict__ Hd, const f16* __restrict__ fw,
                     const float* __restrict__ fb, const float* __restrict__ dec_in,
                     float* __restrict__ out)
{
  __shared__ __align__(16) f16 lA[128 * 64];
  __shared__ __align__(16) f16 lB[128 * 64];
  const int tid = threadIdx.x;
  const int m0 = blockIdx.x * 128;        // rows = t*BB + b, 51200 total
  const int lane = tid & 63, w = tid >> 6;
  const int lrow = lane & 15;
  const int r8 = lane >> 3, s8 = lane & 7;

  const f16* pA[4]; const f16* pB[4];
  f16* dA[4]; f16* dB[4];
  #pragma unroll
  for (int i = 0; i < 4; ++i) {
    int rA = w * 32 + 8 * i;
    dA[i] = lA + rA * 64;
    dB[i] = lB + rA * 64;
    pA[i] = Hd + (size_t)(m0 + rA + r8) * RR + s8 * 8;
    pB[i] = fw + (size_t)(rA + r8) * RR + s8 * 8;   // fc1h padded to 128 rows
  }

  f32x4 acc[2][5];
  #pragma unroll
  for (int a = 0; a < 2; ++a)
    #pragma unroll
    for (int n = 0; n < 5; ++n) acc[a][n] = (f32x4){0.f, 0.f, 0.f, 0.f};

  const int sw0 = (((lane >> 4)) ^ s8) * 8;
  const int sw1 = (((lane >> 4) | 4) ^ s8) * 8;
  const f16* a0 = lA + (w * 32 + lrow) * 64 + sw0;
  const f16* a1 = lA + (w * 32 + lrow) * 64 + sw1;
  const f16* b0 = lB + lrow * 64 + sw0;
  const f16* b1 = lB + lrow * 64 + sw1;

  for (int kt = 0; kt < 16; ++kt) {
    #pragma unroll
    for (int i = 0; i < 4; ++i) { gld16(pA[i], dA[i]); pA[i] += 64; }
    #pragma unroll
    for (int i = 0; i < 4; ++i) { gld16(pB[i], dB[i]); pB[i] += 64; }
    __syncthreads();
    v8h av0[2], av1[2], bv0[5], bv1[5];
    #pragma unroll
    for (int mf = 0; mf < 2; ++mf) {
      av0[mf] = *(const v8h*)(a0 + mf * 1024);
      av1[mf] = *(const v8h*)(a1 + mf * 1024);
    }
    #pragma unroll
    for (int nf = 0; nf < 5; ++nf) {
      bv0[nf] = *(const v8h*)(b0 + nf * 1024);
      bv1[nf] = *(const v8h*)(b1 + nf * 1024);
    }
    #pragma unroll
    for (int mf = 0; mf < 2; ++mf)
      #pragma unroll
      for (int nf = 0; nf < 5; ++nf) {
        acc[mf][nf] = __builtin_amdgcn_mfma_f32_16x16x32_f16(av0[mf], bv0[nf], acc[mf][nf], 0, 0, 0);
        acc[mf][nf] = __builtin_amdgcn_mfma_f32_16x16x32_f16(av1[mf], bv1[nf], acc[mf][nf], 0, 0, 0);
      }
    __syncthreads();
  }
  #pragma unroll
  for (int mf = 0; mf < 2; ++mf) {
    int rbase = m0 + w * 32 + mf * 16 + (lane >> 4) * 4;
    #pragma unroll
    for (int nf = 0; nf < 5; ++nf) {
      int col = nf * 16 + lrow;
      if (col < DI) {
        #pragma unroll
        for (int q = 0; q < 4; ++q) {
          int m = rbase + q;
          int t = m >> 11, b = m & (BB - 1);
          size_t oi = (size_t)b * TT * DI + t * DI + col;
          out[oi] = acc[mf][nf][q] + fb[col] + dec_in[oi];
        }
      }
    }
  }
}

// ---------------- launch ----------------
extern "C" void kernel_launch(void* const* d_in, const int* in_sizes, int n_in,
                              void* d_out, int out_size, void* d_ws, size_t ws_size,
                              hipStream_t stream)
{
  const float* enc_in = (const float*)d_in[0];
  const float* dec_in = (const float*)d_in[1];
  const float* noise  = (const float*)d_in[2];
  const float* Wih_e  = (const float*)d_in[3];
  const float* Whh_e  = (const float*)d_in[4];
  const float* bih_e  = (const float*)d_in[5];
  const float* bhh_e  = (const float*)d_in[6];
  const float* Wih_d  = (const float*)d_in[7];
  const float* Whh_d  = (const float*)d_in[8];
  const float* bih_d  = (const float*)d_in[9];
  const float* bhh_d  = (const float*)d_in[10];
  const float* fc1_w  = (const float*)d_in[11];
  const float* fc1_b  = (const float*)d_in[12];
  const float* mu_w   = (const float*)d_in[13];
  const float* mu_b   = (const float*)d_in[14];
  const float* sig_w  = (const float*)d_in[15];
  const float* sig_b  = (const float*)d_in[16];
  const float* t2v_w  = (const float*)d_in[17];
  const float* t2v_b  = (const float*)d_in[18];
  float* outp = (float*)d_out;

  char* ws = (char*)d_ws;
  size_t off = 0;
  auto alloc = [&](size_t bytes) -> char* {
    char* p = ws + off; off += (bytes + 255) & ~(size_t)255; return p;
  };
  f16*   wq_e   = (f16*)alloc((size_t)4096 * 1280 * 2);
  f16*   wq_d   = (f16*)alloc((size_t)4096 * 1152 * 2);
  f16*   fc1h   = (f16*)alloc((size_t)128 * RR * 2);
  f16*   wt2    = (f16*)alloc((size_t)160 * 128 * 2);
  float* bias_e = (float*)alloc(4096 * 4);
  float* bias_d = (float*)alloc(4096 * 4);
  f16*   feat_e = (f16*)alloc((size_t)SE * BB * 256 * 2);
  f16*   feat_d = (f16*)alloc((size_t)TT * BB * 128 * 2);
  f16*   h_ping = (f16*)alloc((size_t)BB * RR * 2);
  f16*   h_pong = (f16*)alloc((size_t)BB * RR * 2);
  float* cbuf   = (float*)alloc((size_t)BB * RR * 4);
  float* hf32   = (float*)alloc((size_t)BB * RR * 4);
  f16*   Hd     = (f16*)alloc((size_t)TT * BB * RR * 2);
  if (off > ws_size) return;   // workspace too small -> clean failure
  f16*   Xf     = Hd;          // alias: Xf lifetime (prep) disjoint from Hd (decoder)

  // prep
  prep_misc_kernel<<<(BB * RR + 255) / 256, 256, 0, stream>>>(
      cbuf, h_ping, bih_e, bhh_e, bih_d, bhh_d, bias_e, bias_d, fc1_w, fc1h, t2v_w, wt2);
  prep_wq_kernel<<<4096, 256, 0, stream>>>(Whh_e, Wih_e, wq_e, 1280, DI + EE);
  prep_wq_kernel<<<4096, 256, 0, stream>>>(Whh_d, Wih_d, wq_d, 1152, DI);
  xf16_kernel<<<(SE * BB * 256 + 255) / 256, 256, 0, stream>>>(enc_in, Xf, feat_e);
  t2v_kernel<<<SE * (BB / 128), 256, 0, stream>>>(Xf, wt2, t2v_b, feat_e);
  feat_dec_kernel<<<(TT * BB * 128 + 255) / 256, 256, 0, stream>>>(dec_in, feat_d);

  dim3 sgrid(32, 16, 1);   // 1024/32 units x 2048/128 rows

  // encoder: 49 steps, h ping-pong, c in-place
  f16* hcur = h_ping; f16* hnxt = h_pong;
  for (int t = 0; t < SE; ++t) {
    const f16* ft = feat_e + (size_t)t * BB * 256;
    if (t == SE - 1)
      lstm_step_kernel<4, 256, true><<<sgrid, 256, 0, stream>>>(
          hcur, ft, wq_e, bias_e, cbuf, hnxt, hf32);
    else
      lstm_step_kernel<4, 256, false><<<sgrid, 256, 0, stream>>>(
          hcur, ft, wq_e, bias_e, cbuf, hnxt, nullptr);
    f16* tmp = hcur; hcur = hnxt; hnxt = tmp;
  }

  // normalize + noise (reads fp32 h, writes swizzled f16 h into h_ping, c in-place)
  musigma_kernel<<<BB, 256, 0, stream>>>(hf32, cbuf, noise, mu_w, mu_b, sig_w, sig_b, h_ping);

  // decoder: 25 steps, h chained through Hd slices
  const f16* din = h_ping;
  for (int t = 0; t < TT; ++t) {
    f16* hout = Hd + (size_t)t * BB * RR;
    lstm_step_kernel<2, 128, false><<<sgrid, 256, 0, stream>>>(
        din, feat_d + (size_t)t * BB * 128, wq_d, bias_d, cbuf, hout, nullptr);
    din = hout;
  }

  // out = dec_in + Hdec @ fc1^T + fc1_b
  final_fc_kernel<<<(TT * BB) / 128, 256, 0, stream>>>(Hd, fc1h, fc1_b, dec_in, outp);
}

// Round 13
// 2220.374 us; speedup vs baseline: 2.0561x; 1.0330x over previous
//
#include <hip/hip_runtime.h>
#include <hip/hip_bf16.h>
#include <math.h>

// Problem dims
#define DI 69      // input feature dim
#define EE 132     // time2vec dim
#define RR 1024    // rnn size
#define BB 2048    // batch
#define TT 25      // target seq len
#define SE 49      // source seq len - 1

typedef _Float16 f16;
typedef _Float16 v8h __attribute__((ext_vector_type(8)));
typedef float f32x4 __attribute__((ext_vector_type(4)));

__device__ __forceinline__ float sigm(float x) { return 1.0f / (1.0f + __expf(-x)); }
__device__ __forceinline__ float tanhf_fast(float x) {
  float e = __expf(2.0f * x);          // inf-safe: x>>0 -> 1, x<<0 -> -1
  return 1.0f - 2.0f / (e + 1.0f);
}

// async global->LDS, 16B per lane. LDS dest is wave-uniform base; lane l
// writes bytes [base + l*16, base + l*16 + 16) from its own global address.
typedef const __attribute__((address_space(1))) char* gas1p;
typedef __attribute__((address_space(3))) char* las3p;
__device__ __forceinline__ void gld16(const void* g, void* l) {
  __builtin_amdgcn_global_load_lds((gas1p)g, (las3p)l, 16, 0, 0);
}

// Global h/feat/W layouts are PRE-SWIZZLED: element (row, k) lives at
// k' = k ^ ((row&7)<<3) (XOR on 16B-slot bits within each 64-half K-group).
// Staging to LDS is fully linear (global_load_lds); ds_reads apply the
// same XOR -> conflict-free (both-sides rule).

// ---------------- prep kernels ----------------

__global__ void prep_misc_kernel(float* __restrict__ c, f16* __restrict__ h0,
                                 const float* __restrict__ bih_e, const float* __restrict__ bhh_e,
                                 const float* __restrict__ bih_d, const float* __restrict__ bhh_d,
                                 float* __restrict__ bias_e, float* __restrict__ bias_d,
                                 const float* __restrict__ fc1_w, f16* __restrict__ fc1h,
                                 const float* __restrict__ t2v_w, f16* __restrict__ wt2)
{
  int i = blockIdx.x * 256 + threadIdx.x;   // grid covers BB*RR = 2M
  if (i < BB * RR) { c[i] = 0.0f; h0[i] = (f16)0.0f; }
  if (i < 4096) { bias_e[i] = bih_e[i] + bhh_e[i]; bias_d[i] = bih_d[i] + bhh_d[i]; }
  if (i < 128 * RR) {   // fc1h padded to 128 rows, swizzled
    int dr = i >> 10, k = i & 1023;
    int kd = k ^ ((dr & 7) << 3);
    fc1h[(dr << 10) | kd] = (f16)((dr < DI) ? fc1_w[dr * RR + k] : 0.0f);
  }
  if (i < 160 * 128) {  // t2v weights: [160 rows pad][128 k pad], swizzled
    int r = i >> 7, k = i & 127;
    float v = (r < EE && k < DI) ? t2v_w[r * DI + k] : 0.0f;
    wt2[(r << 7) | (k ^ ((r & 7) << 3))] = (f16)v;
  }
}

// Pack per-gate weights: Wq[j][k'], j = gate*1024+unit (torch row order),
// k<1024 = Whh row, k>=1024 = Wih row (feature part), zero-padded to KT.
__global__ void prep_wq_kernel(const float* __restrict__ Whh, const float* __restrict__ Wih,
                               f16* __restrict__ Wq, int KT, int DIN)
{
  int j = blockIdx.x;   // 0..4095
  int xo = (j & 7) << 3;
  for (int k = threadIdx.x; k < KT; k += blockDim.x) {
    float v;
    if (k < RR) v = Whh[(size_t)j * RR + k];
    else { int kk = k - RR; v = (kk < DIN) ? Wih[(size_t)j * DIN + kk] : 0.0f; }
    Wq[(size_t)j * KT + (k ^ xo)] = (f16)v;
  }
}

// Vectorized: 1 thread per 8-col group. Swizzle keeps 8-groups contiguous
// (xo is a multiple of 8). Ownership by logical col c: 0..68 x (write Xf+feat;
// c 69..71 garbage-zero overwritten by t2v which runs AFTER), 72..127 Xf pad
// zero, 128..200 t2v-owned (skip), 201..255 feat zero (skip c=200).
__global__ void xf16_kernel(const float* __restrict__ enc_in,
                            f16* __restrict__ Xf, f16* __restrict__ feat)
{
  int idx = blockIdx.x * 256 + threadIdx.x;   // over SE*BB*32 groups
  if (idx >= SE * BB * 32) return;
  int m = idx & 31, row = idx >> 5;           // row = t*BB + b
  int t = row >> 11, b = row & (BB - 1);
  int xo = (b & 7) << 3;
  int c0 = m * 8;
  if (m <= 8) {
    const float* src = enc_in + ((size_t)b * SE + t) * DI + c0;
    f16 v[8];
    #pragma unroll
    for (int e = 0; e < 8; ++e) v[e] = (f16)((c0 + e < DI) ? src[e] : 0.0f);
    *(v8h*)(Xf + (size_t)row * 128 + (c0 ^ xo)) = *(v8h*)v;
    *(v8h*)(feat + (size_t)row * 256 + (c0 ^ xo)) = *(v8h*)v;
  } else if (m <= 15) {                        // c 72..127: Xf zero pad
    v8h z = {};
    *(v8h*)(Xf + (size_t)row * 128 + (c0 ^ xo)) = z;
  } else if (m == 25) {                        // feat c 201..207 (c=200 is t2v's)
    #pragma unroll
    for (int e = 1; e < 8; ++e)
      feat[(size_t)row * 256 + ((200 + e) ^ xo)] = (f16)0.0f;
  } else if (m >= 26) {                        // c 208..255: feat zero
    v8h z = {};
    *(v8h*)(feat + (size_t)row * 256 + (c0 ^ xo)) = z;
  }
}

// sin(X @ Wt2^T + b) -> feat cols 69..200.  MFMA tile: 128 rows x 160 cols,
// K=128 in two 64-k tiles. 256 thr = 4 waves; wave w owns rows w*32..w*32+31.
__global__ __launch_bounds__(256)
void t2v_kernel(const f16* __restrict__ Xf, const f16* __restrict__ wt2,
                const float* __restrict__ t2v_b, f16* __restrict__ feat)
{
  __shared__ __align__(16) f16 lA[128 * 64];   // 16 KB
  __shared__ __align__(16) f16 lB[160 * 64];   // 20 KB
  __shared__ float bl[EE];
  const int tid = threadIdx.x;
  const int m0 = blockIdx.x * 128;             // row = t*BB + b
  const int lane = tid & 63, w = tid >> 6;
  const int lrow = lane & 15;
  const int r8 = lane >> 3, s8 = lane & 7;
  if (tid < EE) bl[tid] = t2v_b[tid];

  f32x4 acc[2][10];
  #pragma unroll
  for (int a = 0; a < 2; ++a)
    #pragma unroll
    for (int n = 0; n < 10; ++n) acc[a][n] = (f32x4){0.f, 0.f, 0.f, 0.f};

  const int sw0 = (((lane >> 4)) ^ s8) * 8;
  const int sw1 = (((lane >> 4) | 4) ^ s8) * 8;

  for (int kt = 0; kt < 2; ++kt) {
    __syncthreads();   // protects bl (kt=0) and lA/lB reuse (kt=1)
    #pragma unroll
    for (int i = 0; i < 4; ++i)
      gld16(Xf + (size_t)(m0 + w * 32 + 8 * i + r8) * 128 + kt * 64 + s8 * 8,
            &lA[(w * 32 + 8 * i) * 64]);
    #pragma unroll
    for (int i = 0; i < 5; ++i)
      gld16(wt2 + (size_t)(w * 40 + 8 * i + r8) * 128 + kt * 64 + s8 * 8,
            &lB[(w * 40 + 8 * i) * 64]);
    __syncthreads();   // drains gld16
    v8h av0[2], av1[2];
    #pragma unroll
    for (int mf = 0; mf < 2; ++mf) {
      av0[mf] = *(const v8h*)(&lA[(w * 32 + mf * 16 + lrow) * 64 + sw0]);
      av1[mf] = *(const v8h*)(&lA[(w * 32 + mf * 16 + lrow) * 64 + sw1]);
    }
    #pragma unroll
    for (int nf = 0; nf < 10; ++nf) {
      v8h bv0 = *(const v8h*)(&lB[(nf * 16 + lrow) * 64 + sw0]);
      v8h bv1 = *(const v8h*)(&lB[(nf * 16 + lrow) * 64 + sw1]);
      #pragma unroll
      for (int mf = 0; mf < 2; ++mf) {
        acc[mf][nf] = __builtin_amdgcn_mfma_f32_16x16x32_f16(av0[mf], bv0, acc[mf][nf], 0, 0, 0);
        acc[mf][nf] = __builtin_amdgcn_mfma_f32_16x16x32_f16(av1[mf], bv1, acc[mf][nf], 0, 0, 0);
      }
    }
  }
  // epilogue: C col=lane&15, row=(lane>>4)*4+q
  #pragma unroll
  for (int nf = 0; nf < 10; ++nf) {
    int e = nf * 16 + lrow;
    if (e < EE) {
      float be = bl[e];
      #pragma unroll
      for (int mf = 0; mf < 2; ++mf) {
        int rbase = m0 + w * 32 + mf * 16 + (lane >> 4) * 4;
        #pragma unroll
        for (int q = 0; q < 4; ++q) {
          int row = rbase + q;
          feat[(size_t)row * 256 + ((69 + e) ^ ((row & 7) << 3))]
              = (f16)__sinf(acc[mf][nf][q] + be);
        }
      }
    }
  }
}

// feat_dec[t][b][0:69] = decoder_inputs[b][t][:], [69:128]=0  (f16, swizzled)
__global__ void feat_dec_kernel(const float* __restrict__ dec_in, f16* __restrict__ feat)
{
  int idx = blockIdx.x * 256 + threadIdx.x;
  if (idx >= TT * BB * 128) return;
  int k = idx & 127;
  int r = idx >> 7;              // t*BB + b
  int t = r >> 11, b = r & (BB - 1);
  float v = (k < DI) ? dec_in[(size_t)b * TT * DI + t * DI + k] : 0.0f;
  feat[((size_t)r << 7) | (k ^ ((b & 7) << 3))] = (f16)v;
}

// ---------------- fused LSTM step: gates GEMM + cell update ----------------
// Block: 128 rows x 32 units (x4 gates out = 128x128). 256 threads = 4 waves.
// COUNTED-VMCNT double-buffer pipeline (T3/T4-lite): stage tile s+2 after
// computing tile s; s_waitcnt vmcnt(8) keeps next tile's 8 loads in flight
// across RAW s_barrier (NOT __syncthreads, which would drain vmcnt to 0 and
// expose full L2 latency -- that was round-4's regression).
// Hazards: bar1 after per-wave vmcnt(8) => all tile-kt loads landed before
// any ds_read; lgkmcnt(0)+memory-clobber+bar2 => all reads done before the
// buffer is restaged. Uniform trip count => no divergent barriers.
template<int FT, int FPAD, bool WF32>
__global__ __launch_bounds__(256, 2)
void lstm_step_kernel(const f16* __restrict__ hin, const f16* __restrict__ feat,
                      const f16* __restrict__ Wq, const float* __restrict__ bias,
                      float* __restrict__ c, f16* __restrict__ hout,
                      float* __restrict__ hf32)
{
  constexpr int NIT = 16 + FT;
  constexpr int KT = NIT * 64;
  __shared__ __align__(16) f16 lA[2][128 * 64];   // 2 x 16 KB
  __shared__ __align__(16) f16 lB[2][128 * 64];   // 2 x 16 KB
  const int tid = threadIdx.x;
  const int m0 = blockIdx.y * 128;
  const int u0 = blockIdx.x * 32;
  const int lane = tid & 63, w = tid >> 6;
  const int wm = w >> 1, wn = w & 1;
  const int lrow = lane & 15;
  const int r8 = lane >> 3, s8 = lane & 7;     // staging: row-in-8, 16B slot

  const f16* pAh[4]; const f16* pAf[4]; const f16* pB[4];
  #pragma unroll
  for (int i = 0; i < 4; ++i) {
    int rA = w * 32 + 8 * i;
    pAh[i] = hin + (size_t)(m0 + rA + r8) * RR + s8 * 8;
    pAf[i] = feat + (size_t)(m0 + rA + r8) * FPAD + s8 * 8;
    pB[i] = Wq + (size_t)(w * 1024 + u0 + 8 * i + r8) * KT + s8 * 8;
  }

  f32x4 acc[4][4];   // [m-frag][gate]
  #pragma unroll
  for (int a = 0; a < 4; ++a)
    #pragma unroll
    for (int g = 0; g < 4; ++g) acc[a][g] = (f32x4){0.f, 0.f, 0.f, 0.f};

  // deswizzled read offsets: slot' = slot ^ (row&7), row&7 == lane&7
  const int sw0 = (((lane >> 4)) ^ s8) * 8;
  const int sw1 = (((lane >> 4) | 4) ^ s8) * 8;
  const int oa = (wm * 64 + lrow) * 64;
  const int ob = (wn * 16 + lrow) * 64;

  auto STAGE = [&](int s) {   // 8 gld16 per wave
    int buf = s & 1;
    #pragma unroll
    for (int i = 0; i < 4; ++i) {
      const f16* src = (s < 16) ? (pAh[i] + s * 64) : (pAf[i] + (s - 16) * 64);
      gld16(src, &lA[buf][(w * 32 + 8 * i) * 64]);
    }
    #pragma unroll
    for (int i = 0; i < 4; ++i)
      gld16(pB[i] + s * 64, &lB[buf][(w * 32 + 8 * i) * 64]);
  };
  auto COMPUTE = [&](int buf) {
    const f16* Ab = &lA[buf][oa];
    const f16* Bb = &lB[buf][ob];
    v8h av0[4], av1[4], bv0[4], bv1[4];
    #pragma unroll
    for (int mf = 0; mf < 4; ++mf) {
      av0[mf] = *(const v8h*)(Ab + mf * 1024 + sw0);
      av1[mf] = *(const v8h*)(Ab + mf * 1024 + sw1);
    }
    #pragma unroll
    for (int g = 0; g < 4; ++g) {
      bv0[g] = *(const v8h*)(Bb + g * 2048 + sw0);
      bv1[g] = *(const v8h*)(Bb + g * 2048 + sw1);
    }
    #pragma unroll
    for (int mf = 0; mf < 4; ++mf)
      #pragma unroll
      for (int g = 0; g < 4; ++g) {
        acc[mf][g] = __builtin_amdgcn_mfma_f32_16x16x32_f16(av0[mf], bv0[g], acc[mf][g], 0, 0, 0);
        acc[mf][g] = __builtin_amdgcn_mfma_f32_16x16x32_f16(av1[mf], bv1[g], acc[mf][g], 0, 0, 0);
      }
  };

  STAGE(0); STAGE(1);   // 16 loads outstanding per wave

  for (int kt = 0; kt < NIT - 1; ++kt) {
    asm volatile("s_waitcnt vmcnt(8)" ::: "memory");   // tile kt landed; kt+1 in flight
    __builtin_amdgcn_s_barrier();
    COMPUTE(kt & 1);
    asm volatile("s_waitcnt lgkmcnt(0)" ::: "memory"); // my ds_reads done
    __builtin_amdgcn_s_barrier();                       // all waves' reads done
    if (kt + 2 < NIT) STAGE(kt + 2);                    // restage this parity's buf
  }
  asm volatile("s_waitcnt vmcnt(0)" ::: "memory");     // last tile landed
  __builtin_amdgcn_s_barrier();
  COMPUTE((NIT - 1) & 1);

  // epilogue: gate order i,f,g,o ; C layout col=lane&15, row=(lane>>4)*4+reg
  const int u = u0 + wn * 16 + lrow;
  const float bi = bias[u], bf = bias[1024 + u], bg = bias[2048 + u], bo = bias[3072 + u];
  #pragma unroll
  for (int mf = 0; mf < 4; ++mf) {
    int rbase = m0 + wm * 64 + mf * 16 + (lane >> 4) * 4;
    #pragma unroll
    for (int q = 0; q < 4; ++q) {
      int r = rbase + q;
      size_t idxc = (size_t)r * RR + u;
      float iv = acc[mf][0][q] + bi;
      float fv = acc[mf][1][q] + bf;
      float gv = acc[mf][2][q] + bg;
      float ov = acc[mf][3][q] + bo;
      float cn = sigm(fv) * c[idxc] + sigm(iv) * tanhf_fast(gv);
      float hn = sigm(ov) * tanhf_fast(cn);
      c[idxc] = cn;
      hout[(size_t)r * RR + (u ^ ((r & 7) << 3))] = (f16)hn;   // swizzled
      if (WF32) hf32[idxc] = hn;                                // plain
    }
  }
}

// ---------------- mu/sigma normalize + noise ----------------
__global__ void musigma_kernel(const float* __restrict__ hf, float* __restrict__ c,
                               const float* __restrict__ noise,
                               const float* __restrict__ mu_w, const float* __restrict__ mu_b,
                               const float* __restrict__ sig_w, const float* __restrict__ sig_b,
                               f16* __restrict__ hout)
{
  int b = blockIdx.x, tid = threadIdx.x;
  __shared__ float red[8];
  __shared__ float musig[2];
  float sh = 0.f, sc = 0.f;
  for (int k = tid; k < RR; k += 256) {
    size_t idx = (size_t)b * RR + k;
    sh += hf[idx] * mu_w[k];
    sc += c[idx] * sig_w[k];
  }
  for (int off = 32; off > 0; off >>= 1) { sh += __shfl_down(sh, off); sc += __shfl_down(sc, off); }
  int wid = tid >> 6;
  if ((tid & 63) == 0) { red[wid] = sh; red[4 + wid] = sc; }
  __syncthreads();
  if (tid == 0) {
    musig[0] = red[0] + red[1] + red[2] + red[3] + mu_b[0];
    musig[1] = red[4] + red[5] + red[6] + red[7] + sig_b[0];
  }
  __syncthreads();
  float mu = musig[0], sg = musig[1];
  int xo = (b & 7) << 3;
  for (int k = tid; k < RR; k += 256) {
    size_t idx = (size_t)b * RR + k;
    float n10 = 10.0f * noise[idx];
    float hh = (hf[idx] - mu) / sg + n10;
    float cc = (c[idx] - mu) / sg + n10;
    hout[(size_t)b * RR + (k ^ xo)] = (f16)hh;   // swizzled
    c[idx] = cc;                                  // plain
  }
}

// ---------------- final residual projection: out = x + Hdec @ fc1^T + b ----------------
__global__ __launch_bounds__(256, 2)
void final_fc_kernel(const f16* __restrict__ Hd, const f16* __restrict__ fw,
                     const float* __restrict__ fb, const float* __restrict__ dec_in,
                     float* __restrict__ out)
{
  __shared__ __align__(16) f16 lA[128 * 64];
  __shared__ __align__(16) f16 lB[128 * 64];
  const int tid = threadIdx.x;
  const int m0 = blockIdx.x * 128;        // rows = t*BB + b, 51200 total
  const int lane = tid & 63, w = tid >> 6;
  const int lrow = lane & 15;
  const int r8 = lane >> 3, s8 = lane & 7;

  const f16* pA[4]; const f16* pB[4];
  f16* dA[4]; f16* dB[4];
  #pragma unroll
  for (int i = 0; i < 4; ++i) {
    int rA = w * 32 + 8 * i;
    dA[i] = lA + rA * 64;
    dB[i] = lB + rA * 64;
    pA[i] = Hd + (size_t)(m0 + rA + r8) * RR + s8 * 8;
    pB[i] = fw + (size_t)(rA + r8) * RR + s8 * 8;   // fc1h padded to 128 rows
  }

  f32x4 acc[2][5];
  #pragma unroll
  for (int a = 0; a < 2; ++a)
    #pragma unroll
    for (int n = 0; n < 5; ++n) acc[a][n] = (f32x4){0.f, 0.f, 0.f, 0.f};

  const int sw0 = (((lane >> 4)) ^ s8) * 8;
  const int sw1 = (((lane >> 4) | 4) ^ s8) * 8;
  const f16* a0 = lA + (w * 32 + lrow) * 64 + sw0;
  const f16* a1 = lA + (w * 32 + lrow) * 64 + sw1;
  const f16* b0 = lB + lrow * 64 + sw0;
  const f16* b1 = lB + lrow * 64 + sw1;

  for (int kt = 0; kt < 16; ++kt) {
    #pragma unroll
    for (int i = 0; i < 4; ++i) { gld16(pA[i], dA[i]); pA[i] += 64; }
    #pragma unroll
    for (int i = 0; i < 4; ++i) { gld16(pB[i], dB[i]); pB[i] += 64; }
    __syncthreads();
    v8h av0[2], av1[2], bv0[5], bv1[5];
    #pragma unroll
    for (int mf = 0; mf < 2; ++mf) {
      av0[mf] = *(const v8h*)(a0 + mf * 1024);
      av1[mf] = *(const v8h*)(a1 + mf * 1024);
    }
    #pragma unroll
    for (int nf = 0; nf < 5; ++nf) {
      bv0[nf] = *(const v8h*)(b0 + nf * 1024);
      bv1[nf] = *(const v8h*)(b1 + nf * 1024);
    }
    #pragma unroll
    for (int mf = 0; mf < 2; ++mf)
      #pragma unroll
      for (int nf = 0; nf < 5; ++nf) {
        acc[mf][nf] = __builtin_amdgcn_mfma_f32_16x16x32_f16(av0[mf], bv0[nf], acc[mf][nf], 0, 0, 0);
        acc[mf][nf] = __builtin_amdgcn_mfma_f32_16x16x32_f16(av1[mf], bv1[nf], acc[mf][nf], 0, 0, 0);
      }
    __syncthreads();
  }
  #pragma unroll
  for (int mf = 0; mf < 2; ++mf) {
    int rbase = m0 + w * 32 + mf * 16 + (lane >> 4) * 4;
    #pragma unroll
    for (int nf = 0; nf < 5; ++nf) {
      int col = nf * 16 + lrow;
      if (col < DI) {
        #pragma unroll
        for (int q = 0; q < 4; ++q) {
          int m = rbase + q;
          int t = m >> 11, b = m & (BB - 1);
          size_t oi = (size_t)b * TT * DI + t * DI + col;
          out[oi] = acc[mf][nf][q] + fb[col] + dec_in[oi];
        }
      }
    }
  }
}

// ---------------- launch ----------------
extern "C" void kernel_launch(void* const* d_in, const int* in_sizes, int n_in,
                              void* d_out, int out_size, void* d_ws, size_t ws_size,
                              hipStream_t stream)
{
  const float* enc_in = (const float*)d_in[0];
  const float* dec_in = (const float*)d_in[1];
  const float* noise  = (const float*)d_in[2];
  const float* Wih_e  = (const float*)d_in[3];
  const float* Whh_e  = (const float*)d_in[4];
  const float* bih_e  = (const float*)d_in[5];
  const float* bhh_e  = (const float*)d_in[6];
  const float* Wih_d  = (const float*)d_in[7];
  const float* Whh_d  = (const float*)d_in[8];
  const float* bih_d  = (const float*)d_in[9];
  const float* bhh_d  = (const float*)d_in[10];
  const float* fc1_w  = (const float*)d_in[11];
  const float* fc1_b  = (const float*)d_in[12];
  const float* mu_w   = (const float*)d_in[13];
  const float* mu_b   = (const float*)d_in[14];
  const float* sig_w  = (const float*)d_in[15];
  const float* sig_b  = (const float*)d_in[16];
  const float* t2v_w  = (const float*)d_in[17];
  const float* t2v_b  = (const float*)d_in[18];
  float* outp = (float*)d_out;

  char* ws = (char*)d_ws;
  size_t off = 0;
  auto alloc = [&](size_t bytes) -> char* {
    char* p = ws + off; off += (bytes + 255) & ~(size_t)255; return p;
  };
  f16*   wq_e   = (f16*)alloc((size_t)4096 * 1280 * 2);
  f16*   wq_d   = (f16*)alloc((size_t)4096 * 1152 * 2);
  f16*   fc1h   = (f16*)alloc((size_t)128 * RR * 2);
  f16*   wt2    = (f16*)alloc((size_t)160 * 128 * 2);
  float* bias_e = (float*)alloc(4096 * 4);
  float* bias_d = (float*)alloc(4096 * 4);
  f16*   feat_e = (f16*)alloc((size_t)SE * BB * 256 * 2);
  f16*   feat_d = (f16*)alloc((size_t)TT * BB * 128 * 2);
  f16*   h_ping = (f16*)alloc((size_t)BB * RR * 2);
  f16*   h_pong = (f16*)alloc((size_t)BB * RR * 2);
  float* cbuf   = (float*)alloc((size_t)BB * RR * 4);
  float* hf32   = (float*)alloc((size_t)BB * RR * 4);
  f16*   Hd     = (f16*)alloc((size_t)TT * BB * RR * 2);
  if (off > ws_size) return;   // workspace too small -> clean failure
  f16*   Xf     = Hd;          // alias: Xf lifetime (prep) disjoint from Hd (decoder)

  // prep
  prep_misc_kernel<<<(BB * RR + 255) / 256, 256, 0, stream>>>(
      cbuf, h_ping, bih_e, bhh_e, bih_d, bhh_d, bias_e, bias_d, fc1_w, fc1h, t2v_w, wt2);
  prep_wq_kernel<<<4096, 256, 0, stream>>>(Whh_e, Wih_e, wq_e, 1280, DI + EE);
  prep_wq_kernel<<<4096, 256, 0, stream>>>(Whh_d, Wih_d, wq_d, 1152, DI);
  xf16_kernel<<<(SE * BB * 32 + 255) / 256, 256, 0, stream>>>(enc_in, Xf, feat_e);
  t2v_kernel<<<SE * (BB / 128), 256, 0, stream>>>(Xf, wt2, t2v_b, feat_e);
  feat_dec_kernel<<<(TT * BB * 128 + 255) / 256, 256, 0, stream>>>(dec_in, feat_d);

  dim3 sgrid(32, 16, 1);   // 1024/32 units x 2048/128 rows

  // encoder: 49 steps, h ping-pong, c in-place
  f16* hcur = h_ping; f16* hnxt = h_pong;
  for (int t = 0; t < SE; ++t) {
    const f16* ft = feat_e + (size_t)t * BB * 256;
    if (t == SE - 1)
      lstm_step_kernel<4, 256, true><<<sgrid, 256, 0, stream>>>(
          hcur, ft, wq_e, bias_e, cbuf, hnxt, hf32);
    else
      lstm_step_kernel<4, 256, false><<<sgrid, 256, 0, stream>>>(
          hcur, ft, wq_e, bias_e, cbuf, hnxt, nullptr);
    f16* tmp = hcur; hcur = hnxt; hnxt = tmp;
  }

  // normalize + noise (reads fp32 h, writes swizzled f16 h into h_ping, c in-place)
  musigma_kernel<<<BB, 256, 0, stream>>>(hf32, cbuf, noise, mu_w, mu_b, sig_w, sig_b, h_ping);

  // decoder: 25 steps, h chained through Hd slices
  const f16* din = h_ping;
  for (int t = 0; t < TT; ++t) {
    f16* hout = Hd + (size_t)t * BB * RR;
    lstm_step_kernel<2, 128, false><<<sgrid, 256, 0, stream>>>(
        din, feat_d + (size_t)t * BB * 128, wq_d, bias_d, cbuf, hout, nullptr);
    din = hout;
  }

  // out = dec_in + Hdec @ fc1^T + fc1_b
  final_fc_kernel<<<(TT * BB) / 128, 256, 0, stream>>>(Hd, fc1h, fc1_b, dec_in, outp);
}